// Round 7
// baseline (152.605 us; speedup 1.0000x reference)
//
#include <hip/hip_runtime.h>
#include <hip/hip_bf16.h>

#define N_ROWS 8192
#define BATCH 4096
#define DIM 256

#define NB 64           // 128-row blocks along each side
#define BR 128          // rows (and cols) per pair-block side
#define CT 32           // cols per LDS tile
#define NT 4            // tiles per block (BR/CT)
#define NBLK (NB * (NB + 1) / 2)   // 2080 pair blocks
#define TILEB (CT * 512)           // 16 KB per tile, LINEAR (XOR swizzle)
#define KEXP 2.8853900817779268f   // 2*log2(e): exp(2*dot) = exp2(dot*KEXP)

typedef __attribute__((ext_vector_type(8))) short bfrag8;
typedef __attribute__((ext_vector_type(4))) float facc4;

// async global->LDS, 16B per lane; LDS dest = wave-uniform base + lane*16
#define GLOAD_LDS16(g, l) __builtin_amdgcn_global_load_lds( \
    (const __attribute__((address_space(1))) unsigned int*)(g), \
    (__attribute__((address_space(3))) unsigned int*)(l), 16, 0, 0)

// decode linear pair id k -> (bi, bj), bi <= bj, over NB blocks
__device__ __forceinline__ void pair_decode(int k, int& bi, int& bj) {
    bi = (int)(0.5f * (129.0f - sqrtf(16641.0f - 8.0f * (float)k)));
    if (bi < 0) bi = 0;
    if (bi > NB - 1) bi = NB - 1;
    while (bi * (129 - bi) / 2 > k) --bi;
    while ((bi + 1) * (128 - bi) / 2 <= k) ++bi;
    bj = bi + (k - bi * (129 - bi) / 2);
}

// ---------------- Kernel A: normalize + cast to bf16 -------------------
__global__ __launch_bounds__(256) void normalize_kernel(
    const float* __restrict__ zA, const float* __restrict__ zB,
    __hip_bfloat16* __restrict__ zn) {
    int tid = threadIdx.x;
    int wave = tid >> 6, lane = tid & 63;
    int row = blockIdx.x * 4 + wave;
    const float* src = (row < BATCH) ? (zA + (size_t)row * DIM)
                                     : (zB + (size_t)(row - BATCH) * DIM);
    float4 v = ((const float4*)src)[lane];
    float ss = v.x * v.x + v.y * v.y + v.z * v.z + v.w * v.w;
    #pragma unroll
    for (int m = 32; m; m >>= 1) ss += __shfl_xor(ss, m);
    float inv = 1.0f / fmaxf(sqrtf(ss), 1e-8f);
    union { ushort4 u; __hip_bfloat16 h[4]; } o;
    o.h[0] = __float2bfloat16(v.x * inv);
    o.h[1] = __float2bfloat16(v.y * inv);
    o.h[2] = __float2bfloat16(v.z * inv);
    o.h[3] = __float2bfloat16(v.w * inv);
    ((ushort4*)zn)[(size_t)row * (DIM / 4) + lane] = o.u;
}

// ---------------- Kernel B1: pair-block GEMM -> exp tile E -------------
// SPLIT-EPILOGUE ABLATION (r0-r6 accounting: ~30us idle invariant across
// all structural changes; the never-varied suspect is the fused per-subtile
// epilogue chain exp->add->shfl_xor->colbuf). B1 keeps r6's DMA/LDS/MFMA
// core but ends each subtile with exp2 + coalesced float4 store of the
// exp'd tile E[k][C][R] (col-major in R). No cross-lane, no colbuf, no
// in-loop reductions: stores are fire-and-forget so subtile n+1 overlaps
// subtile n's tail. pos (raw dot) extraction stays here (cheap).
__global__ __launch_bounds__(256, 3) void ntxent_gemm(
    const __hip_bfloat16* __restrict__ zn_,
    float* __restrict__ E, float* __restrict__ pp) {
    const char* zn = (const char*)zn_;
    __shared__ char lds[2 * TILEB] __attribute__((aligned(1024)));
    int tid = threadIdx.x, lane = tid & 63, wave = tid >> 6;
    int quad = lane >> 4, l15 = lane & 15;

    // XCD-aware swizzle (bijective: 2080 % 8 == 0); B2 uses the SAME map so
    // block k of B2 lands on the same XCD -> E-tile is L2-local.
    int bid = blockIdx.x;
    int k = (bid & 7) * (NBLK / 8) + (bid >> 3);
    int bi, bj; pair_decode(k, bi, bj);
    bool diagblk = (bi == bj);
    bool posblk  = (bj == (bi ^ 32));   // holds the (i, i^4096) pairs

    int row0 = bi * BR + wave * 32;   // this wave's 32 global rows
    const char* gBt = zn + (size_t)bj * BR * 512;
    float* Et = E + (size_t)k * (BR * BR);   // 64KB tile, layout [C][R]

    // staging source offsets (pre-inverse-swizzled global, linear LDS dest)
    int h = lane >> 5;
    int olane = (lane & 31) * 16;
    unsigned sofs[4];
    #pragma unroll
    for (int c = 0; c < 4; c++) {
        int col = wave * 8 + 2 * c + h;
        sofs[c] = (unsigned)(col * 512 + (olane ^ ((col & 7) << 4)));
    }

    #pragma unroll
    for (int c = 0; c < 4; c++)     // stage tile 0
        GLOAD_LDS16(gBt + sofs[c], lds + wave * 4096 + c * 1024);

    // A fragments: 2 tiles of 16 rows, full K=256 (overlaps tile-0 DMA)
    bfrag8 a[2][8];
    #pragma unroll
    for (int s = 0; s < 2; s++) {
        const char* ap = zn + (size_t)(row0 + s * 16 + l15) * 512 + quad * 16;
        #pragma unroll
        for (int ks = 0; ks < 8; ks++)
            a[s][ks] = *(const bfrag8*)(ap + ks * 64);
    }

    __syncthreads();

    for (int t = 0; t < NT; t++) {
        char* cur = lds + (t & 1) * TILEB;
        char* nxt = lds + ((t + 1) & 1) * TILEB;
        if (t + 1 < NT) {
            const char* g = gBt + (size_t)(t + 1) * TILEB;
            #pragma unroll
            for (int c = 0; c < 4; c++)
                GLOAD_LDS16(g + sofs[c], nxt + wave * 4096 + c * 1024);
        }

        #pragma unroll
        for (int sub = 0; sub < 2; sub++) {
            int c2 = sub * 16 + l15;
            const char* bp = cur + c2 * 512;
            unsigned sw = (unsigned)((c2 & 7) << 4);
            bfrag8 bf[8];
            #pragma unroll
            for (int ks = 0; ks < 8; ks++) {
                unsigned o = (unsigned)(quad * 16 + ks * 64);
                bf[ks] = *(const bfrag8*)(bp + (o ^ sw));
            }

            facc4 acc[2];
            acc[0] = (facc4){0.f, 0.f, 0.f, 0.f};
            acc[1] = (facc4){0.f, 0.f, 0.f, 0.f};
            #pragma unroll
            for (int ks = 0; ks < 8; ks++) {
                acc[0] = __builtin_amdgcn_mfma_f32_16x16x32_bf16(a[0][ks], bf[ks], acc[0], 0, 0, 0);
                acc[1] = __builtin_amdgcn_mfma_f32_16x16x32_bf16(a[1][ks], bf[ks], acc[1], 0, 0, 0);
            }

            int C = t * CT + sub * 16 + l15;   // within-block col
            #pragma unroll
            for (int s = 0; s < 2; s++) {
                int R0 = wave * 32 + s * 16 + quad * 4;  // within-block row base
                int dd = C - R0;
                if (posblk) {   // pos pair (grow, grow^4096) lives at C==R
                    #pragma unroll
                    for (int r = 0; r < 4; r++)
                        if (dd == r) {
                            int grow = bi * BR + R0 + r;
                            float d = acc[s][r];
                            pp[grow] = d;
                            pp[grow ^ BATCH] = d;
                        }
                }
                float e0 = __builtin_amdgcn_exp2f(acc[s][0] * KEXP);
                float e1 = __builtin_amdgcn_exp2f(acc[s][1] * KEXP);
                float e2 = __builtin_amdgcn_exp2f(acc[s][2] * KEXP);
                float e3 = __builtin_amdgcn_exp2f(acc[s][3] * KEXP);
                if (diagblk) {  // mask true diagonal (C==R)
                    e0 = (dd == 0) ? 0.0f : e0;
                    e1 = (dd == 1) ? 0.0f : e1;
                    e2 = (dd == 2) ? 0.0f : e2;
                    e3 = (dd == 3) ? 0.0f : e3;
                }
                // E[C][R0..R0+3]: 16B-aligned, 16 full lines per (s) store
                *(float4*)(Et + (size_t)C * BR + R0) = make_float4(e0, e1, e2, e3);
            }
        }
        __syncthreads();
    }
}

// ---------------- Kernel B2: per-tile row/col sums of E ----------------
// One block per pair-block; same swizzle -> same XCD -> E-tile L2/L3-hot.
//   col-sums -> ep[bj*128+C][bi]   (skip on diag blocks)
//   row-sums -> ep[bi*128+R][bj]
// Pure coalesced streaming; diag already zeroed in E.
__global__ __launch_bounds__(256) void ntxent_sums(
    const float* __restrict__ E, float* __restrict__ ep) {
    int bid = blockIdx.x;
    int k = (bid & 7) * (NBLK / 8) + (bid >> 3);
    int bi, bj; pair_decode(k, bi, bj);
    bool diagblk = (bi == bj);
    const float* T = E + (size_t)k * (BR * BR);
    int tid = threadIdx.x;

    // pass 1: col-sums. thread pair (C = tid>>1, h = tid&1): 16 float4 contiguous
    {
        int C = tid >> 1, h = tid & 1;
        const float4* p = (const float4*)(T + (size_t)C * BR + h * 64);
        float cs = 0.0f;
        #pragma unroll
        for (int i = 0; i < 16; i++) {
            float4 v = p[i];
            cs += (v.x + v.y) + (v.z + v.w);
        }
        cs += __shfl_xor(cs, 1);
        if (!diagblk && h == 0)
            ep[(size_t)(bj * BR + C) * NB + bi] = cs;
    }

    // pass 2: row-sums. thread (rg = tid>>3, cc = tid&7): float4 of 4 rows,
    // 16 cols each; reduce over the 8 cc lanes.
    {
        int rg = tid >> 3, cc = tid & 7;
        float r0 = 0.f, r1 = 0.f, r2 = 0.f, r3 = 0.f;
        #pragma unroll
        for (int i = 0; i < 16; i++) {
            int C = cc * 16 + i;
            float4 v = *(const float4*)(T + (size_t)C * BR + rg * 4);
            r0 += v.x; r1 += v.y; r2 += v.z; r3 += v.w;
        }
        #pragma unroll
        for (int m = 1; m < 8; m <<= 1) {
            r0 += __shfl_xor(r0, m);
            r1 += __shfl_xor(r1, m);
            r2 += __shfl_xor(r2, m);
            r3 += __shfl_xor(r3, m);
        }
        if (cc == 0) {
            size_t base = (size_t)(bi * BR + rg * 4) * NB + bj;
            ep[base] = r0;
            ep[base + NB] = r1;
            ep[base + 2 * NB] = r2;
            ep[base + 3 * NB] = r3;
        }
    }
}

// ---------------- Kernel C: combine + log + final reduce ---------------
__global__ __launch_bounds__(256) void finalize_kernel(
    const float* __restrict__ ep, const float* __restrict__ pp,
    float* __restrict__ out) {
    int tid = threadIdx.x;
    int i = blockIdx.x * 256 + tid;
    const float4* epr = (const float4*)(ep + (size_t)i * NB);
    float e = 0.0f;
    #pragma unroll
    for (int s = 0; s < NB / 4; s++) {
        float4 v = epr[s];
        e += (v.x + v.y) + (v.z + v.w);
    }
    float v = __logf(e) - 2.0f * pp[i];
    #pragma unroll
    for (int m = 32; m; m >>= 1) v += __shfl_xor(v, m);
    __shared__ float wsum[4];
    if ((tid & 63) == 0) wsum[tid >> 6] = v;
    __syncthreads();
    if (tid == 0)
        atomicAdd(out, (wsum[0] + wsum[1] + wsum[2] + wsum[3]) * (1.0f / N_ROWS));
}

extern "C" void kernel_launch(void* const* d_in, const int* in_sizes, int n_in,
                              void* d_out, int out_size, void* d_ws, size_t ws_size,
                              hipStream_t stream) {
    const float* zA = (const float*)d_in[0];
    const float* zB = (const float*)d_in[1];
    float* out = (float*)d_out;
    char* ws = (char*)d_ws;
    __hip_bfloat16* zn = (__hip_bfloat16*)ws;                       // 4 MB
    float* ep = (float*)(ws + (size_t)N_ROWS * DIM * 2);            // 2 MB
    float* pp = ep + (size_t)N_ROWS * NB;                           // 32 KB
    float* E  = (float*)(ws + ((size_t)8 << 20));                   // 133 MB @ +8MB

    hipMemsetAsync(out, 0, sizeof(float), stream);
    normalize_kernel<<<N_ROWS / 4, 256, 0, stream>>>(zA, zB, zn);
    ntxent_gemm<<<NBLK, 256, 0, stream>>>(zn, E, pp);
    ntxent_sums<<<NBLK, 256, 0, stream>>>(E, ep);
    finalize_kernel<<<N_ROWS / 256, 256, 0, stream>>>(ep, pp, out);
}

// Round 8
// 116.329 us; speedup vs baseline: 1.3118x; 1.3118x over previous
//
#include <hip/hip_runtime.h>
#include <hip/hip_bf16.h>

#define N_ROWS 8192
#define BATCH 4096
#define DIM 256

#define NP 32           // 256-row panels
#define PR 256          // rows per panel
#define CW 128          // cols per block (chunk)
#define NJ 64           // col chunks along N
#define CT 32           // cols per LDS tile
#define NT 4            // tiles per block (CW/CT)
#define NBLK 1056       // 16 pairs x 66 chunks (= 8 x 132, swizzle-bijective)
#define TILEB (CT * 512)           // 16 KB per tile, LINEAR (XOR swizzle)
#define KEXP 2.8853900817779268f   // 2*log2(e): exp(2*dot) = exp2(dot*KEXP)

typedef __attribute__((ext_vector_type(8))) short bfrag8;
typedef __attribute__((ext_vector_type(4))) float facc4;

// async global->LDS, 16B per lane; LDS dest = wave-uniform base + lane*16
#define GLOAD_LDS16(g, l) __builtin_amdgcn_global_load_lds( \
    (const __attribute__((address_space(1))) unsigned int*)(g), \
    (__attribute__((address_space(3))) unsigned int*)(l), 16, 0, 0)

// ---------------- Kernel A: normalize + cast to bf16 -------------------
__global__ __launch_bounds__(256) void normalize_kernel(
    const float* __restrict__ zA, const float* __restrict__ zB,
    __hip_bfloat16* __restrict__ zn) {
    int tid = threadIdx.x;
    int wave = tid >> 6, lane = tid & 63;
    int row = blockIdx.x * 4 + wave;
    const float* src = (row < BATCH) ? (zA + (size_t)row * DIM)
                                     : (zB + (size_t)(row - BATCH) * DIM);
    float4 v = ((const float4*)src)[lane];
    float ss = v.x * v.x + v.y * v.y + v.z * v.z + v.w * v.w;
    #pragma unroll
    for (int m = 32; m; m >>= 1) ss += __shfl_xor(ss, m);
    float inv = 1.0f / fmaxf(sqrtf(ss), 1e-8f);
    union { ushort4 u; __hip_bfloat16 h[4]; } o;
    o.h[0] = __float2bfloat16(v.x * inv);
    o.h[1] = __float2bfloat16(v.y * inv);
    o.h[2] = __float2bfloat16(v.z * inv);
    o.h[3] = __float2bfloat16(v.w * inv);
    ((ushort4*)zn)[(size_t)row * (DIM / 4) + lane] = o.u;
}

// ---------------- Kernel B: symmetric panel-chunk sim + exp-sum --------
// LONG-BLOCK GEOMETRY (r0's 64-rows/wave, proven 2x MfmaUtil of the
// 32-row variants; per-block prologue amortized over 2x work; pure-
// arithmetic pair decode). 32 row-panels of 256 rows, pair-balanced
// (m <-> 31-m, 66 chunks/pair); 128-col chunks -> 1056 uniform blocks.
//   row-sums of exp -> ep[rows of p][slot j]      (slots 2p..63)
//   col-sums of exp -> ep[cols of j][slot p]      (slots 0..p-1; skip on
//                                                  diag-band jp==p)
// Slots [p,2p) of each row are never written; finalize skips them.
// launch_bounds(256,2): a[4][8]=128 + bf[8]=32 + acc/es/misc fits 256
// (r0-proven); (256,3)'s 170-cap would spill -- don't.
__global__ __launch_bounds__(256, 2) void ntxent_main(
    const __hip_bfloat16* __restrict__ zn_,
    float* __restrict__ ep, float* __restrict__ pp) {
    const char* zn = (const char*)zn_;
    __shared__ char lds[2 * TILEB] __attribute__((aligned(1024)));
    __shared__ float colbuf[4][CW];
    int tid = threadIdx.x, lane = tid & 63, wave = tid >> 6;
    int quad = lane >> 4, l15 = lane & 15;

    // XCD-aware swizzle (bijective: 1056 = 8*132)
    int bid = blockIdx.x;
    int k = (bid & 7) * (NBLK / 8) + (bid >> 3);

    // pair-balanced decode: pair m = {panel m, panel 31-m}; panel p owns
    // chunks [2p, 64) -> (64-2m) + (2m+2) = 66 chunks per pair.
    int m = k / 66, c = k % 66;
    int n0 = 64 - 2 * m;
    int p, j;
    if (c < n0) { p = m;      j = 2 * m + c; }
    else        { p = 31 - m; j = 2 * p + (c - n0); }

    int jp = j >> 1, jd = j & 1;          // 256-panel of this col chunk
    bool diagband = (jp == p);            // chunk overlaps own diagonal band
    bool posband  = (jp == (p ^ 16));     // chunk holds (i, i^4096) partners

    int row0 = p * PR + wave * 64;        // this wave's 64 global rows
    const char* gBt = zn + (size_t)j * CW * 512;

    // staging source offsets (pre-inverse-swizzled global, linear LDS dest)
    int h = lane >> 5;
    int olane = (lane & 31) * 16;
    unsigned sofs[4];
    #pragma unroll
    for (int cc = 0; cc < 4; cc++) {
        int col = wave * 8 + 2 * cc + h;
        sofs[cc] = (unsigned)(col * 512 + (olane ^ ((col & 7) << 4)));
    }

    #pragma unroll
    for (int cc = 0; cc < 4; cc++)        // stage tile 0
        GLOAD_LDS16(gBt + sofs[cc], lds + wave * 4096 + cc * 1024);

    // A fragments: 4 tiles of 16 rows (64 rows/wave), full K=256
    bfrag8 a[4][8];
    #pragma unroll
    for (int s = 0; s < 4; s++) {
        const char* ap = zn + (size_t)(row0 + s * 16 + l15) * 512 + quad * 16;
        #pragma unroll
        for (int ks = 0; ks < 8; ks++)
            a[s][ks] = *(const bfrag8*)(ap + ks * 64);
    }

    float es[4][4];
    #pragma unroll
    for (int s = 0; s < 4; s++)
        #pragma unroll
        for (int r = 0; r < 4; r++) es[s][r] = 0.f;

    __syncthreads();

    for (int t = 0; t < NT; t++) {
        char* cur = lds + (t & 1) * TILEB;
        char* nxt = lds + ((t + 1) & 1) * TILEB;
        if (t + 1 < NT) {
            const char* g = gBt + (size_t)(t + 1) * TILEB;
            #pragma unroll
            for (int cc = 0; cc < 4; cc++)
                GLOAD_LDS16(g + sofs[cc], nxt + wave * 4096 + cc * 1024);
        }

        #pragma unroll
        for (int sub = 0; sub < 2; sub++) {
            int c2 = sub * 16 + l15;
            const char* bp = cur + c2 * 512;
            unsigned sw = (unsigned)((c2 & 7) << 4);
            bfrag8 bf[8];
            #pragma unroll
            for (int ks = 0; ks < 8; ks++) {
                unsigned o = (unsigned)(quad * 16 + ks * 64);
                bf[ks] = *(const bfrag8*)(bp + (o ^ sw));
            }

            facc4 acc[4];
            #pragma unroll
            for (int s = 0; s < 4; s++) acc[s] = (facc4){0.f, 0.f, 0.f, 0.f};
            #pragma unroll
            for (int ks = 0; ks < 8; ks++)
                #pragma unroll
                for (int s = 0; s < 4; s++)
                    acc[s] = __builtin_amdgcn_mfma_f32_16x16x32_bf16(a[s][ks], bf[ks], acc[s], 0, 0, 0);

            int C = t * CT + sub * 16 + l15;   // within-chunk col [0,128)
            float ce = 0.0f;
            #pragma unroll
            for (int s = 0; s < 4; s++) {
                // match condition (diag or pos): global row == matching row
                // <=> R (= wave*64+s*16+quad*4+r) == C + 128*jd
                int dd = C + 128 * jd - (wave * 64 + s * 16 + quad * 4);
                if (posband) {
                    #pragma unroll
                    for (int r = 0; r < 4; r++)
                        if (dd == r) {
                            int grow = row0 + s * 16 + quad * 4 + r;
                            float d = acc[s][r];       // raw dot; finalize scales
                            pp[grow] = d;
                            pp[grow ^ BATCH] = d;      // symmetric partner
                        }
                }
                #pragma unroll
                for (int r = 0; r < 4; r++) {
                    float e = __builtin_amdgcn_exp2f(acc[s][r] * KEXP);
                    if (diagband && dd == r) e = 0.0f; // mask true diagonal
                    es[s][r] += e; ce += e;
                }
            }
            // column partial sums (transposed contribution); diag-band
            // blocks skip col-side (their transposed cells are covered by
            // row-side of same-panel blocks)
            if (!diagband) {
                ce += __shfl_xor(ce, 16);
                ce += __shfl_xor(ce, 32);
                if (lane < 16) colbuf[wave][t * CT + sub * 16 + l15] = ce;
            }
        }

        __syncthreads();
    }

    // row-side: reduce es across the 16 column-lanes, write ep[row][j]
    #pragma unroll
    for (int s = 0; s < 4; s++)
        #pragma unroll
        for (int r = 0; r < 4; r++) {
            float e = es[s][r];
            #pragma unroll
            for (int mm = 1; mm < 16; mm <<= 1) e += __shfl_xor(e, mm);
            if (l15 == 0)
                ep[(size_t)(row0 + s * 16 + quad * 4 + r) * NJ + j] = e;
        }

    // col-side: sum the 4 wave partials, write ep[cols of j][p]
    // (colbuf complete: loop ended with __syncthreads)
    if (!diagband && tid < CW) {
        float v = colbuf[0][tid] + colbuf[1][tid] + colbuf[2][tid] + colbuf[3][tid];
        ep[(size_t)(j * CW + tid) * NJ + p] = v;
    }
}

// ---------------- Kernel C: combine + log + final reduce ---------------
__global__ __launch_bounds__(256) void finalize_kernel(
    const float* __restrict__ ep, const float* __restrict__ pp,
    float* __restrict__ out) {
    int tid = threadIdx.x;
    int i = blockIdx.x * 256 + tid;
    int p = blockIdx.x;   // 256-aligned blocks: panel uniform per block
    const float* epr = ep + (size_t)i * NJ;
    float e = 0.0f;
    // slots [0,p) = col-side, [2p,64) = row-side; [p,2p) never written
    for (int s = 0; s < p; s++) e += epr[s];
    for (int s = 2 * p; s < NJ; s++) e += epr[s];
    float v = __logf(e) - 2.0f * pp[i];
    #pragma unroll
    for (int mm = 32; mm; mm >>= 1) v += __shfl_xor(v, mm);
    __shared__ float wsum[4];
    if ((tid & 63) == 0) wsum[tid >> 6] = v;
    __syncthreads();
    if (tid == 0)
        atomicAdd(out, (wsum[0] + wsum[1] + wsum[2] + wsum[3]) * (1.0f / N_ROWS));
}

extern "C" void kernel_launch(void* const* d_in, const int* in_sizes, int n_in,
                              void* d_out, int out_size, void* d_ws, size_t ws_size,
                              hipStream_t stream) {
    const float* zA = (const float*)d_in[0];
    const float* zB = (const float*)d_in[1];
    float* out = (float*)d_out;
    char* ws = (char*)d_ws;
    __hip_bfloat16* zn = (__hip_bfloat16*)ws;                       // 4 MB
    float* ep = (float*)(ws + (size_t)N_ROWS * DIM * 2);            // 8192*64 floats (2 MB)
    float* pp = ep + (size_t)N_ROWS * NJ;                           // 32 KB

    hipMemsetAsync(out, 0, sizeof(float), stream);
    normalize_kernel<<<N_ROWS / 4, 256, 0, stream>>>(zA, zB, zn);
    ntxent_main<<<NBLK, 256, 0, stream>>>(zn, ep, pp);
    finalize_kernel<<<N_ROWS / 256, 256, 0, stream>>>(ep, pp, out);
}